// Round 11
// baseline (104.970 us; speedup 1.0000x reference)
//
#include <hip/hip_runtime.h>
#include <math.h>

#define BS 16
#define NA 2048
#define NB 2048
#define NK 64
#define NV 64
#define EPS 1e-8f

typedef float        f32x4  __attribute__((ext_vector_type(4)));
typedef __bf16       bf16x8 __attribute__((ext_vector_type(8)));
typedef short        s16x8  __attribute__((ext_vector_type(8)));
typedef unsigned int u32x4  __attribute__((ext_vector_type(4)));
typedef unsigned short u16x8 __attribute__((ext_vector_type(8)));

// ---- MFMA wrapper: prefer bf16-vector signature, SFINAE-fallback to short8 ----
template <typename V>
__device__ __forceinline__ auto mfma_impl(V a, V b, f32x4 c, int)
    -> decltype(__builtin_amdgcn_mfma_f32_16x16x32_bf16(a, b, c, 0, 0, 0)) {
    return __builtin_amdgcn_mfma_f32_16x16x32_bf16(a, b, c, 0, 0, 0);
}
template <typename V>
__device__ __forceinline__ auto mfma_impl(V a, V b, f32x4 c, long)
    -> decltype(__builtin_amdgcn_mfma_f32_16x16x32_bf16(
           __builtin_bit_cast(s16x8, a), __builtin_bit_cast(s16x8, b), c, 0, 0, 0)) {
    return __builtin_amdgcn_mfma_f32_16x16x32_bf16(
        __builtin_bit_cast(s16x8, a), __builtin_bit_cast(s16x8, b), c, 0, 0, 0);
}
__device__ __forceinline__ f32x4 mfma_bf16(u32x4 a, u32x4 b, f32x4 c) {
    bf16x8 av = __builtin_bit_cast(bf16x8, a);
    bf16x8 bv = __builtin_bit_cast(bf16x8, b);
    return mfma_impl(av, bv, c, 0);
}

__device__ __forceinline__ unsigned short f2bf(float x) {
    unsigned u = __builtin_bit_cast(unsigned, x);
    unsigned r = (u + 0x7FFFu + ((u >> 16) & 1u)) >> 16;
    return (unsigned short)r;
}
__device__ __forceinline__ u16x8 pk8(f32x4 a, f32x4 b) {
    u16x8 p;
    p[0] = f2bf(a[0]); p[1] = f2bf(a[1]); p[2] = f2bf(a[2]); p[3] = f2bf(a[3]);
    p[4] = f2bf(b[0]); p[5] = f2bf(b[1]); p[6] = f2bf(b[2]); p[7] = f2bf(b[3]);
    return p;
}
__device__ __forceinline__ f32x4 ldg4(const float* p) { return *(const f32x4*)p; }

// raw barrier: lgkmcnt-only wait, leaves global prefetch loads in flight
__device__ __forceinline__ void bar_lgkm() {
    asm volatile("s_waitcnt lgkmcnt(0)" ::: "memory");
    __builtin_amdgcn_s_barrier();
}

// swizzle within a [64 rows][128 B] tile: 16B chunk index ^= (row & 7)
__device__ __forceinline__ int swz128(int lin) {
    const int r = lin >> 7;
    const int c16 = (lin >> 4) & 7;
    return (r << 7) + ((c16 ^ (r & 7)) << 4) + (lin & 15);
}

// ======================= prepass kernels =======================
__global__ __launch_bounds__(256)
void conv_k_kernel(const float* __restrict__ key, unsigned short* __restrict__ kb) {
    size_t i = ((size_t)blockIdx.x * 256 + threadIdx.x) * 8;
    f32x4 a = *(const f32x4*)(key + i);
    f32x4 b = *(const f32x4*)(key + i + 4);
    *(u16x8*)(kb + i) = pk8(a, b);
}

__global__ __launch_bounds__(256)
void transpose_v_kernel(const float* __restrict__ v, unsigned short* __restrict__ vt) {
    __shared__ float tile[64][65];
    const int b = blockIdx.y, at = blockIdx.x * 64;
    const float* Vb = v + (size_t)b * NA * NV;
    unsigned short* Vtb = vt + (size_t)b * NV * NA;
    const int r = threadIdx.x >> 2, c = (threadIdx.x & 3) * 16;
    #pragma unroll
    for (int j = 0; j < 4; ++j)
        *(f32x4*)&tile[r][c + 4 * j] = ldg4(Vb + (size_t)(at + r) * NV + c + 4 * j);
    __syncthreads();
    u16x8 p0, p1;
    #pragma unroll
    for (int j = 0; j < 8; ++j) p0[j] = f2bf(tile[c + j][r]);
    #pragma unroll
    for (int j = 0; j < 8; ++j) p1[j] = f2bf(tile[c + 8 + j][r]);
    *(u16x8*)(Vtb + (size_t)r * NA + at + c) = p0;
    *(u16x8*)(Vtb + (size_t)r * NA + at + c + 8) = p1;
}

// ======================= lsum kernel (pass A, a-split 4-way) =======================
// grid 4096 = 16 b x 64 n-tiles x 4 a-chunks; per block: 32 n x 512 a (8 tiles).
// Writes lpart[b][achunk][n] partial sums (no atomics; deterministic).
#define BN2 32
#define LKD0 0
#define LKD1 8192
#define LLRED 16384
#define LSMEM 16896

__global__ __launch_bounds__(256, 4)
void lsum_kernel(const unsigned short* __restrict__ kb,   // [BS][NA][NK] bf16
                 const float* __restrict__ qf,             // [BS][NB][NK] f32
                 float* __restrict__ lpart)                // [BS][4][NB]
{
    __shared__ __align__(16) char smem[LSMEM];
    const int tid = threadIdx.x, w = tid >> 6, lane = tid & 63;
    const int lr = lane & 15, lg = lane >> 4;

    // XCD swizzle: 4096 % 8 == 0; XCD x gets 512 consecutive logical blocks.
    const int lin = blockIdx.x;
    const int swz = (lin & 7) * 512 + (lin >> 3);
    const int b = swz >> 8, achunk = (swz >> 6) & 3, nb = (swz & 63) * BN2;

    const char* Kc = (const char*)(kb + (size_t)b * NA * NK) + achunk * (512 * NK * 2);
    const float* Qb = qf + (size_t)b * NB * NK;

    // Q fragments: f32 load + in-register bf16 convert
    u32x4 af[2][2];
    #pragma unroll
    for (int t = 0; t < 2; ++t)
        #pragma unroll
        for (int c = 0; c < 2; ++c) {
            const float* qp = Qb + (size_t)(nb + t * 16 + lr) * NK + c * 32 + lg * 8;
            f32x4 qa = ldg4(qp);
            f32x4 qb2 = ldg4(qp + 4);
            af[t][c] = __builtin_bit_cast(u32x4, pk8(qa, qb2));
        }

    const int lin0 = tid * 16;
    const int lin1 = tid * 16 + 4096;
    const int kdst0 = swz128(lin0), kdst1 = swz128(lin1);
    const int row = w * 16 + lr;
    int kfro[2];
    #pragma unroll
    for (int c = 0; c < 2; ++c)
        kfro[c] = row * 128 + (((c * 4 + lg) ^ (row & 7)) << 4);

    u32x4 kr0 = *(const u32x4*)(Kc + lin0);
    u32x4 kr1 = *(const u32x4*)(Kc + lin1);
    *(u32x4*)(smem + LKD0 + kdst0) = kr0;
    *(u32x4*)(smem + LKD0 + kdst1) = kr1;
    bar_lgkm();

    float lacc[2][4] = {};
    for (int i = 0; i < 8; ++i) {
        const int p = i & 1;
        if (i + 1 < 8) {
            kr0 = *(const u32x4*)(Kc + (i + 1) * 8192 + lin0);
            kr1 = *(const u32x4*)(Kc + (i + 1) * 8192 + lin1);
        }
        const char* kbuf = smem + (p ? LKD1 : LKD0);
        u32x4 kf0 = *(const u32x4*)(kbuf + kfro[0]);
        u32x4 kf1 = *(const u32x4*)(kbuf + kfro[1]);
        #pragma unroll
        for (int t = 0; t < 2; ++t) {
            f32x4 acc = {0.f, 0.f, 0.f, 0.f};
            acc = mfma_bf16(af[t][0], kf0, acc);
            acc = mfma_bf16(af[t][1], kf1, acc);
            #pragma unroll
            for (int r = 0; r < 4; ++r)
                lacc[t][r] += __expf(acc[r] * 0.125f);
        }
        if (i + 1 < 8) {
            char* kbn = smem + (p ? LKD0 : LKD1);
            *(u32x4*)(kbn + kdst0) = kr0;
            *(u32x4*)(kbn + kdst1) = kr1;
        }
        bar_lgkm();
    }

    #pragma unroll
    for (int t = 0; t < 2; ++t)
        #pragma unroll
        for (int r = 0; r < 4; ++r) {
            float v = lacc[t][r];
            v += __shfl_xor(v, 1); v += __shfl_xor(v, 2);
            v += __shfl_xor(v, 4); v += __shfl_xor(v, 8);
            lacc[t][r] = v;
        }
    if (lr == 0) {
        float* lp = (float*)(smem + LLRED);
        #pragma unroll
        for (int t = 0; t < 2; ++t)
            #pragma unroll
            for (int r = 0; r < 4; ++r)
                lp[w * 32 + t * 16 + lg * 4 + r] = lacc[t][r];
    }
    __syncthreads();
    if (tid < 32) {
        const float* lp = (const float*)(smem + LLRED);
        lpart[((size_t)b * 4 + achunk) * NB + nb + tid] =
            lp[tid] + lp[32 + tid] + lp[64 + tid] + lp[96 + tid];
    }
}

// ======================= main kernel (R10 pass B + epilogue; pass A removed) =======================
#define NT  32
#define KD0 0
#define KD1 8192
#define VD0 16384
#define VD1 24576
#define ESB 32768
#define LRED 36864
#define LINV 37376
#define SMEMSZ 37504

__global__ __launch_bounds__(256, 4)
void attn_main8_kernel(const unsigned short* __restrict__ kb,   // [BS][NA][NK] bf16
                       const float* __restrict__ qf,            // [BS][NB][NK] f32
                       const unsigned short* __restrict__ vtb,  // [BS][NV][NA] bf16
                       const float* __restrict__ lpart,         // [BS][4][NB]
                       float* __restrict__ out,                 // [BS][NV][NB]
                       float* __restrict__ wout)                // [BS][NA][NB]
{
    __shared__ __align__(16) char smem[SMEMSZ];
    const int tid = threadIdx.x, w = tid >> 6, lane = tid & 63;
    const int lr = lane & 15, lg = lane >> 4;

    // XCD-aware bijective swizzle (proven +2.6% in R7)
    const int lin = blockIdx.x;
    const int swz = (lin & 7) * 128 + (lin >> 3);
    const int b = swz >> 6, nb = (swz & 63) * BN2;

    const char* Kb = (const char*)(kb + (size_t)b * NA * NK);
    const char* Vt = (const char*)(vtb + (size_t)b * NV * NA);
    const float* Qb = qf + (size_t)b * NB * NK;
    float* Wb = wout + (size_t)b * NA * NB;
    float* Ob = out + (size_t)b * NV * NB;

    // Q fragments: load f32, convert to bf16 in-register (once)
    u32x4 af[2][2];
    #pragma unroll
    for (int t = 0; t < 2; ++t)
        #pragma unroll
        for (int c = 0; c < 2; ++c) {
            const float* qp = Qb + (size_t)(nb + t * 16 + lr) * NK + c * 32 + lg * 8;
            f32x4 qa = ldg4(qp);
            f32x4 qb2 = ldg4(qp + 4);
            af[t][c] = __builtin_bit_cast(u32x4, pk8(qa, qb2));
        }

    // linv from the 4 a-chunk partials
    if (tid < 32) {
        const float* lpb = lpart + (size_t)b * 4 * NB + nb;
        float s = lpb[tid] + lpb[NB + tid] + lpb[2 * NB + tid] + lpb[3 * NB + tid];
        ((float*)(smem + LINV))[tid] = 1.0f / s;
    }
    __syncthreads();
    f32x4 linv[2];
    linv[0] = *(const f32x4*)(smem + LINV + (lg * 4) * 4);
    linv[1] = *(const f32x4*)(smem + LINV + (16 + lg * 4) * 4);

    // staging offsets (per thread)
    const int lin0 = tid * 16;
    const int lin1 = tid * 16 + 4096;
    const int kdst0 = swz128(lin0), kdst1 = swz128(lin1);
    const int vsrc0 = ((lin0 >> 7) * (NA * 2)) + (lin0 & 127);
    const int vsrc1 = ((lin1 >> 7) * (NA * 2)) + (lin1 & 127);

    // fragment read offsets (bytes within a tile buffer)
    const int row = w * 16 + lr;          // K-row (a) for S; V-row (v) for PV
    int kfro[2];
    #pragma unroll
    for (int c = 0; c < 2; ++c)
        kfro[c] = row * 128 + (((c * 4 + lg) ^ (row & 7)) << 4);
    int esro[2][2];
    #pragma unroll
    for (int t = 0; t < 2; ++t)
        #pragma unroll
        for (int c = 0; c < 2; ++c) {
            const int rr = t * 16 + lr;
            esro[t][c] = rr * 128 + (((c * 4 + lg) ^ (rr & 7)) << 4);
        }
    int eswo[2][4];
    #pragma unroll
    for (int t = 0; t < 2; ++t)
        #pragma unroll
        for (int r = 0; r < 4; ++r) {
            const int n = t * 16 + lg * 4 + r;
            eswo[t][r] = n * 128 + (((w * 2 + (lr >> 3)) ^ (n & 7)) << 4) + (lr & 7) * 2;
        }

    // =============== PASS B: w = e/l (store), PV accumulate ===============
    f32x4 pacc[2] = {{0.f,0.f,0.f,0.f},{0.f,0.f,0.f,0.f}};

    u32x4 kr0 = *(const u32x4*)(Kb + lin0);
    u32x4 kr1 = *(const u32x4*)(Kb + lin1);
    u32x4 vr0 = *(const u32x4*)(Vt + vsrc0);
    u32x4 vr1 = *(const u32x4*)(Vt + vsrc1);
    *(u32x4*)(smem + KD0 + kdst0) = kr0;
    *(u32x4*)(smem + KD0 + kdst1) = kr1;
    *(u32x4*)(smem + VD0 + kdst0) = vr0;
    *(u32x4*)(smem + VD0 + kdst1) = vr1;
    bar_lgkm();

    for (int i = 0; i < NT; ++i) {
        const int p = i & 1;
        if (i + 1 < NT) {
            kr0 = *(const u32x4*)(Kb + (i + 1) * 8192 + lin0);
            kr1 = *(const u32x4*)(Kb + (i + 1) * 8192 + lin1);
            vr0 = *(const u32x4*)(Vt + (i + 1) * 128 + vsrc0);
            vr1 = *(const u32x4*)(Vt + (i + 1) * 128 + vsrc1);
        }
        const char* kbuf = smem + (p ? KD1 : KD0);
        const char* vbuf = smem + (p ? VD1 : VD0);
        u32x4 kf0 = *(const u32x4*)(kbuf + kfro[0]);
        u32x4 kf1 = *(const u32x4*)(kbuf + kfro[1]);
        const int at = i * 64;
        #pragma unroll
        for (int t = 0; t < 2; ++t) {
            f32x4 acc = {0.f, 0.f, 0.f, 0.f};
            acc = mfma_bf16(af[t][0], kf0, acc);
            acc = mfma_bf16(af[t][1], kf1, acc);
            f32x4 wv;
            #pragma unroll
            for (int r = 0; r < 4; ++r)
                wv[r] = __expf(acc[r] * 0.125f) * linv[t][r];
            *(f32x4*)(Wb + (size_t)(at + row) * NB + nb + t * 16 + lg * 4) = wv;
            #pragma unroll
            for (int r = 0; r < 4; ++r)
                *(unsigned short*)(smem + ESB + eswo[t][r]) = f2bf(wv[r]);
        }
        bar_lgkm();   // Es visible; prefetch global loads stay in flight

        u32x4 pa[2][2];
        #pragma unroll
        for (int t = 0; t < 2; ++t)
            #pragma unroll
            for (int c = 0; c < 2; ++c)
                pa[t][c] = *(const u32x4*)(smem + ESB + esro[t][c]);
        u32x4 vf0 = *(const u32x4*)(vbuf + kfro[0]);
        u32x4 vf1 = *(const u32x4*)(vbuf + kfro[1]);
        #pragma unroll
        for (int t = 0; t < 2; ++t) {
            pacc[t] = mfma_bf16(pa[t][0], vf0, pacc[t]);
            pacc[t] = mfma_bf16(pa[t][1], vf1, pacc[t]);
        }
        if (i + 1 < NT) {
            char* kbn = smem + (p ? KD0 : KD1);
            char* vbn = smem + (p ? VD0 : VD1);
            *(u32x4*)(kbn + kdst0) = kr0;
            *(u32x4*)(kbn + kdst1) = kr1;
            *(u32x4*)(vbn + kdst0) = vr0;
            *(u32x4*)(vbn + kdst1) = vr1;
        }
        bar_lgkm();
    }

    // =============== epilogue: normalize over v (ddof=1), transpose, store ===============
    __syncthreads();
    float* vals = (float*)smem;   // [32][66], aliases Kd
    #pragma unroll
    for (int t = 0; t < 2; ++t)
        #pragma unroll
        for (int r = 0; r < 4; ++r)
            vals[(t * 16 + lg * 4 + r) * 66 + w * 16 + lr] = pacc[t][r];
    __syncthreads();
    {
        const int n = tid >> 3, v0 = (tid & 7) * 8;
        float sv[8], s1 = 0.f, s2 = 0.f;
        #pragma unroll
        for (int j = 0; j < 8; ++j) {
            float x = vals[n * 66 + v0 + j];
            sv[j] = x; s1 += x; s2 = fmaf(x, x, s2);
        }
        s1 += __shfl_xor(s1, 1); s2 += __shfl_xor(s2, 1);
        s1 += __shfl_xor(s1, 2); s2 += __shfl_xor(s2, 2);
        s1 += __shfl_xor(s1, 4); s2 += __shfl_xor(s2, 4);
        const float mu = s1 * (1.0f / 64.0f);
        float var = (s2 - 64.0f * mu * mu) * (1.0f / 63.0f);
        var = fmaxf(var, 0.0f);
        const float istd = 1.0f / (sqrtf(var) + EPS);
        #pragma unroll
        for (int j = 0; j < 8; ++j)
            vals[n * 66 + v0 + j] = (sv[j] - mu) * istd;
    }
    __syncthreads();
    {
        const int v = tid >> 2, q = (tid & 3) * 8;
        f32x4 o0, o1;
        #pragma unroll
        for (int j = 0; j < 4; ++j) o0[j] = vals[(q + j) * 66 + v];
        #pragma unroll
        for (int j = 0; j < 4; ++j) o1[j] = vals[(q + 4 + j) * 66 + v];
        *(f32x4*)(Ob + (size_t)v * NB + nb + q) = o0;
        *(f32x4*)(Ob + (size_t)v * NB + nb + q + 4) = o1;
    }
}

// ======================= fallback (round-2 kernel) =======================
#define SQ 72
#define OSTR 68
#define SMEM_BYTES 38144

__global__ __launch_bounds__(256, 2)
void attn_fb_kernel(const float* __restrict__ key, const float* __restrict__ query,
                    const float* __restrict__ value, float* __restrict__ out,
                    float* __restrict__ wout)
{
    __shared__ __align__(16) char smem[SMEM_BYTES];
    unsigned short* Qs = (unsigned short*)(smem);
    unsigned short* Ks = (unsigned short*)(smem + 9216);
    unsigned short* Vts = (unsigned short*)(smem + 18432);
    unsigned short* Es = (unsigned short*)(smem + 27648);
    float* linv_s = (float*)(smem + 36864);
    float (*lred)[64] = (float (*)[64])(smem + 37120);
    float* outl = (float*)(smem + 18432);

    const int tid = threadIdx.x, wave = tid >> 6, lane = tid & 63;
    const int lr = lane & 15, lg = lane >> 4;
    const int b = blockIdx.y, nb = blockIdx.x * 64, aw = wave * 16;

    const float* Kb = key + (size_t)b * NA * NK;
    const float* Qb = query + (size_t)b * NB * NK;
    const float* Vb = value + (size_t)b * NA * NV;
    float* Wb = wout + (size_t)b * NA * NB;
    float* Ob = out + (size_t)b * NV * NB;

    {
        const int r = tid >> 2, c = (tid & 3) * 16;
        const float* src = Qb + (size_t)(nb + r) * NK + c;
        f32x4 q0 = ldg4(src), q1 = ldg4(src + 4), q2 = ldg4(src + 8), q3 = ldg4(src + 12);
        *(u16x8*)&Qs[r * SQ + c] = pk8(q0, q1);
        *(u16x8*)&Qs[r * SQ + c + 8] = pk8(q2, q3);
    }
    float lacc[4][4] = {};
    for (int at = 0; at < NA; at += 64) {
        {
            const int r = tid >> 2, c = (tid & 3) * 16;
            const float* src = Kb + (size_t)(at + r) * NK + c;
            f32x4 k0 = ldg4(src), k1 = ldg4(src + 4), k2 = ldg4(src + 8), k3 = ldg4(src + 12);
            *(u16x8*)&Ks[r * SQ + c] = pk8(k0, k1);
            *(u16x8*)&Ks[r * SQ + c + 8] = pk8(k2, k3);
        }
        __syncthreads();
        u32x4 bf0 = *(const u32x4*)&Ks[(aw + lr) * SQ + (lg * 8)];
        u32x4 bf1 = *(const u32x4*)&Ks[(aw + lr) * SQ + (32 + lg * 8)];
        #pragma unroll
        for (int t = 0; t < 4; ++t) {
            f32x4 acc = {0.f, 0.f, 0.f, 0.f};
            u32x4 af0 = *(const u32x4*)&Qs[(t * 16 + lr) * SQ + (lg * 8)];
            u32x4 af1 = *(const u32x4*)&Qs[(t * 16 + lr) * SQ + (32 + lg * 8)];
            acc = mfma_bf16(af0, bf0, acc);
            acc = mfma_bf16(af1, bf1, acc);
            #pragma unroll
            for (int r = 0; r < 4; ++r) lacc[t][r] += __expf(acc[r] * 0.125f);
        }
        __syncthreads();
    }
    #pragma unroll
    for (int t = 0; t < 4; ++t)
        #pragma unroll
        for (int r = 0; r < 4; ++r) {
            float v = lacc[t][r];
            v += __shfl_xor(v, 1); v += __shfl_xor(v, 2);
            v += __shfl_xor(v, 4); v += __shfl_xor(v, 8);
            lacc[t][r] = v;
        }
    if (lr == 0)
        #pragma unroll
        for (int t = 0; t < 4; ++t)
            #pragma unroll
            for (int r = 0; r < 4; ++r)
                lred[wave][t * 16 + lg * 4 + r] = lacc[t][r];
    __syncthreads();
    if (tid < 64) {
        float s = lred[0][tid] + lred[1][tid] + lred[2][tid] + lred[3][tid];
        linv_s[tid] = 1.0f / s;
    }
    __syncthreads();
    f32x4 linv[4];
    #pragma unroll
    for (int t = 0; t < 4; ++t) linv[t] = *(const f32x4*)&linv_s[t * 16 + lg * 4];

    f32x4 pacc[4] = {{0.f,0.f,0.f,0.f},{0.f,0.f,0.f,0.f},{0.f,0.f,0.f,0.f},{0.f,0.f,0.f,0.f}};
    for (int at = 0; at < NA; at += 64) {
        {
            const int r = tid >> 2, c = (tid & 3) * 16;
            const float* src = Kb + (size_t)(at + r) * NK + c;
            f32x4 k0 = ldg4(src), k1 = ldg4(src + 4), k2 = ldg4(src + 8), k3 = ldg4(src + 12);
            *(u16x8*)&Ks[r * SQ + c] = pk8(k0, k1);
            *(u16x8*)&Ks[r * SQ + c + 8] = pk8(k2, k3);
        }
        {
            const int ap = (tid & 31) * 2, q = tid >> 5;
            const float* v0p = Vb + (size_t)(at + ap) * NV + q * 8;
            const float* v1p = v0p + NV;
            f32x4 a0 = ldg4(v0p), a1 = ldg4(v0p + 4);
            f32x4 b0 = ldg4(v1p), b1 = ldg4(v1p + 4);
            #pragma unroll
            for (int j = 0; j < 4; ++j) {
                unsigned int w0 = (unsigned)f2bf(a0[j]) | ((unsigned)f2bf(b0[j]) << 16);
                *(unsigned int*)&Vts[(q * 8 + j) * SQ + ap] = w0;
                unsigned int w1 = (unsigned)f2bf(a1[j]) | ((unsigned)f2bf(b1[j]) << 16);
                *(unsigned int*)&Vts[(q * 8 + 4 + j) * SQ + ap] = w1;
            }
        }
        __syncthreads();
        u32x4 bf0 = *(const u32x4*)&Ks[(aw + lr) * SQ + (lg * 8)];
        u32x4 bf1 = *(const u32x4*)&Ks[(aw + lr) * SQ + (32 + lg * 8)];
        #pragma unroll
        for (int t = 0; t < 4; ++t) {
            f32x4 acc = {0.f, 0.f, 0.f, 0.f};
            u32x4 af0 = *(const u32x4*)&Qs[(t * 16 + lr) * SQ + (lg * 8)];
            u32x4 af1 = *(const u32x4*)&Qs[(t * 16 + lr) * SQ + (32 + lg * 8)];
            acc = mfma_bf16(af0, bf0, acc);
            acc = mfma_bf16(af1, bf1, acc);
            f32x4 wv;
            #pragma unroll
            for (int r = 0; r < 4; ++r) wv[r] = __expf(acc[r] * 0.125f) * linv[t][r];
            *(f32x4*)(Wb + (size_t)(at + aw + lr) * NB + nb + t * 16 + lg * 4) = wv;
            #pragma unroll
            for (int r = 0; r < 4; ++r)
                Es[(t * 16 + lg * 4 + r) * SQ + (aw + lr)] = f2bf(wv[r]);
        }
        __syncthreads();
        u32x4 paf0 = *(const u32x4*)&Es[(wave * 16 + lr) * SQ + (lg * 8)];
        u32x4 paf1 = *(const u32x4*)&Es[(wave * 16 + lr) * SQ + (32 + lg * 8)];
        #pragma unroll
        for (int t = 0; t < 4; ++t) {
            u32x4 vb0 = *(const u32x4*)&Vts[(t * 16 + lr) * SQ + (lg * 8)];
            u32x4 vb1 = *(const u32x4*)&Vts[(t * 16 + lr) * SQ + (32 + lg * 8)];
            pacc[t] = mfma_bf16(paf0, vb0, pacc[t]);
            pacc[t] = mfma_bf16(paf1, vb1, pacc[t]);
        }
        __syncthreads();
    }
    float mu[4], istd[4];
    #pragma unroll
    for (int r = 0; r < 4; ++r) {
        float s1 = 0.f, s2 = 0.f;
        #pragma unroll
        for (int t = 0; t < 4; ++t) { float x = pacc[t][r]; s1 += x; s2 = fmaf(x, x, s2); }
        s1 += __shfl_xor(s1, 1); s2 += __shfl_xor(s2, 1);
        s1 += __shfl_xor(s1, 2); s2 += __shfl_xor(s2, 2);
        s1 += __shfl_xor(s1, 4); s2 += __shfl_xor(s2, 4);
        s1 += __shfl_xor(s1, 8); s2 += __shfl_xor(s2, 8);
        float m = s1 * (1.0f / 64.0f);
        float var = (s2 - 64.0f * m * m) * (1.0f / 63.0f);
        var = fmaxf(var, 0.0f);
        mu[r] = m; istd[r] = 1.0f / (sqrtf(var) + EPS);
    }
    #pragma unroll
    for (int t = 0; t < 4; ++t)
        #pragma unroll
        for (int r = 0; r < 4; ++r)
            outl[(t * 16 + lr) * OSTR + wave * 16 + lg * 4 + r] = (pacc[t][r] - mu[r]) * istd[r];
    __syncthreads();
    {
        const int v = tid >> 2, c = (tid & 3) * 16;
        float* dst = Ob + (size_t)v * NB + nb + c;
        const float* srcr = &outl[v * OSTR + c];
        #pragma unroll
        for (int j = 0; j < 4; ++j)
            *(f32x4*)(dst + 4 * j) = *(const f32x4*)(srcr + 4 * j);
    }
}

extern "C" void kernel_launch(void* const* d_in, const int* in_sizes, int n_in,
                              void* d_out, int out_size, void* d_ws, size_t ws_size,
                              hipStream_t stream) {
    const float* key   = (const float*)d_in[0];
    const float* query = (const float*)d_in[1];
    const float* value = (const float*)d_in[2];
    float* out  = (float*)d_out;                   // [BS][NV][NB]
    float* wout = out + (size_t)BS * NV * NB;      // [BS][NA][NB]

    const size_t elems = (size_t)BS * NA * NK;     // 2,097,152 per array
    const size_t need = 2 * elems * sizeof(unsigned short)
                      + (size_t)BS * 4 * NB * sizeof(float);
    if (ws_size >= need) {
        unsigned short* kbuf = (unsigned short*)d_ws;
        unsigned short* vt = kbuf + elems;
        float* lpart = (float*)(vt + elems);
        conv_k_kernel<<<dim3((unsigned)(elems / (256 * 8))), 256, 0, stream>>>(key, kbuf);
        transpose_v_kernel<<<dim3(NA / 64, BS), 256, 0, stream>>>(value, vt);
        lsum_kernel<<<dim3(4096), 256, 0, stream>>>(kbuf, query, lpart);
        attn_main8_kernel<<<dim3(1024), 256, 0, stream>>>(kbuf, query, vt, lpart, out, wout);
    } else {
        attn_fb_kernel<<<dim3(NB / 64, BS), 256, 0, stream>>>(key, query, value, out, wout);
    }
}

// Round 12
// 91.348 us; speedup vs baseline: 1.1491x; 1.1491x over previous
//
#include <hip/hip_runtime.h>
#include <math.h>

#define BS 16
#define NA 2048
#define NB 2048
#define NK 64
#define NV 64
#define EPS 1e-8f

typedef float        f32x4  __attribute__((ext_vector_type(4)));
typedef __bf16       bf16x8 __attribute__((ext_vector_type(8)));
typedef short        s16x8  __attribute__((ext_vector_type(8)));
typedef unsigned int u32x4  __attribute__((ext_vector_type(4)));
typedef unsigned short u16x8 __attribute__((ext_vector_type(8)));

// ---- MFMA wrapper: prefer bf16-vector signature, SFINAE-fallback to short8 ----
template <typename V>
__device__ __forceinline__ auto mfma_impl(V a, V b, f32x4 c, int)
    -> decltype(__builtin_amdgcn_mfma_f32_16x16x32_bf16(a, b, c, 0, 0, 0)) {
    return __builtin_amdgcn_mfma_f32_16x16x32_bf16(a, b, c, 0, 0, 0);
}
template <typename V>
__device__ __forceinline__ auto mfma_impl(V a, V b, f32x4 c, long)
    -> decltype(__builtin_amdgcn_mfma_f32_16x16x32_bf16(
           __builtin_bit_cast(s16x8, a), __builtin_bit_cast(s16x8, b), c, 0, 0, 0)) {
    return __builtin_amdgcn_mfma_f32_16x16x32_bf16(
        __builtin_bit_cast(s16x8, a), __builtin_bit_cast(s16x8, b), c, 0, 0, 0);
}
__device__ __forceinline__ f32x4 mfma_bf16(u32x4 a, u32x4 b, f32x4 c) {
    bf16x8 av = __builtin_bit_cast(bf16x8, a);
    bf16x8 bv = __builtin_bit_cast(bf16x8, b);
    return mfma_impl(av, bv, c, 0);
}

__device__ __forceinline__ unsigned short f2bf(float x) {
    unsigned u = __builtin_bit_cast(unsigned, x);
    unsigned r = (u + 0x7FFFu + ((u >> 16) & 1u)) >> 16;
    return (unsigned short)r;
}
__device__ __forceinline__ u16x8 pk8(f32x4 a, f32x4 b) {
    u16x8 p;
    p[0] = f2bf(a[0]); p[1] = f2bf(a[1]); p[2] = f2bf(a[2]); p[3] = f2bf(a[3]);
    p[4] = f2bf(b[0]); p[5] = f2bf(b[1]); p[6] = f2bf(b[2]); p[7] = f2bf(b[3]);
    return p;
}
__device__ __forceinline__ f32x4 ldg4(const float* p) { return *(const f32x4*)p; }

// raw barrier: lgkmcnt-only wait, leaves global prefetch loads in flight
__device__ __forceinline__ void bar_lgkm() {
    asm volatile("s_waitcnt lgkmcnt(0)" ::: "memory");
    __builtin_amdgcn_s_barrier();
}

// swizzle within a [64 rows][128 B] tile: 16B chunk index ^= (row & 7)
__device__ __forceinline__ int swz128(int lin) {
    const int r = lin >> 7;
    const int c16 = (lin >> 4) & 7;
    return (r << 7) + ((c16 ^ (r & 7)) << 4) + (lin & 15);
}

// ======================= prepass kernels =======================
// K conversion only (Q is converted in-register in the main kernel)
__global__ __launch_bounds__(256)
void conv_k_kernel(const float* __restrict__ key, unsigned short* __restrict__ kb) {
    size_t i = ((size_t)blockIdx.x * 256 + threadIdx.x) * 8;
    f32x4 a = *(const f32x4*)(key + i);
    f32x4 b = *(const f32x4*)(key + i + 4);
    *(u16x8*)(kb + i) = pk8(a, b);
}

__global__ __launch_bounds__(256)
void transpose_v_kernel(const float* __restrict__ v, unsigned short* __restrict__ vt) {
    __shared__ float tile[64][65];
    const int b = blockIdx.y, at = blockIdx.x * 64;
    const float* Vb = v + (size_t)b * NA * NV;
    unsigned short* Vtb = vt + (size_t)b * NV * NA;
    const int r = threadIdx.x >> 2, c = (threadIdx.x & 3) * 16;
    #pragma unroll
    for (int j = 0; j < 4; ++j)
        *(f32x4*)&tile[r][c + 4 * j] = ldg4(Vb + (size_t)(at + r) * NV + c + 4 * j);
    __syncthreads();
    u16x8 p0, p1;
    #pragma unroll
    for (int j = 0; j < 8; ++j) p0[j] = f2bf(tile[c + j][r]);
    #pragma unroll
    for (int j = 0; j < 8; ++j) p1[j] = f2bf(tile[c + 8 + j][r]);
    *(u16x8*)(Vtb + (size_t)r * NA + at + c) = p0;
    *(u16x8*)(Vtb + (size_t)r * NA + at + c + 8) = p1;
}

// ======================= main kernel (R10: R9 structure; Q converted in-register) =======================
#define BN2 32
#define NT  32
#define KD0 0
#define KD1 8192
#define VD0 16384
#define VD1 24576
#define ESB 32768
#define LRED 36864
#define LINV 37376
#define SMEMSZ 37504

__global__ __launch_bounds__(256, 4)
void attn_main7_kernel(const unsigned short* __restrict__ kb,   // [BS][NA][NK] bf16
                       const float* __restrict__ qf,            // [BS][NB][NK] f32
                       const unsigned short* __restrict__ vtb,  // [BS][NV][NA] bf16
                       float* __restrict__ out,                 // [BS][NV][NB]
                       float* __restrict__ wout)                // [BS][NA][NB]
{
    __shared__ __align__(16) char smem[SMEMSZ];
    const int tid = threadIdx.x, w = tid >> 6, lane = tid & 63;
    const int lr = lane & 15, lg = lane >> 4;

    // XCD-aware bijective swizzle (proven +2.6% in R7)
    const int lin = blockIdx.x;
    const int swz = (lin & 7) * 128 + (lin >> 3);
    const int b = swz >> 6, nb = (swz & 63) * BN2;

    const char* Kb = (const char*)(kb + (size_t)b * NA * NK);
    const char* Vt = (const char*)(vtb + (size_t)b * NV * NA);
    const float* Qb = qf + (size_t)b * NB * NK;
    float* Wb = wout + (size_t)b * NA * NB;
    float* Ob = out + (size_t)b * NV * NB;

    // Q fragments: load f32, convert to bf16 in-register (once, outside both loops)
    u32x4 af[2][2];
    #pragma unroll
    for (int t = 0; t < 2; ++t)
        #pragma unroll
        for (int c = 0; c < 2; ++c) {
            const float* qp = Qb + (size_t)(nb + t * 16 + lr) * NK + c * 32 + lg * 8;
            f32x4 qa = ldg4(qp);
            f32x4 qb2 = ldg4(qp + 4);
            af[t][c] = __builtin_bit_cast(u32x4, pk8(qa, qb2));
        }

    // staging offsets (per thread)
    const int lin0 = tid * 16;
    const int lin1 = tid * 16 + 4096;
    const int kdst0 = swz128(lin0), kdst1 = swz128(lin1);
    const int vsrc0 = ((lin0 >> 7) * (NA * 2)) + (lin0 & 127);
    const int vsrc1 = ((lin1 >> 7) * (NA * 2)) + (lin1 & 127);

    // fragment read offsets (bytes within a tile buffer)
    const int row = w * 16 + lr;          // K-row (a) for S; V-row (v) for PV
    int kfro[2];
    #pragma unroll
    for (int c = 0; c < 2; ++c)
        kfro[c] = row * 128 + (((c * 4 + lg) ^ (row & 7)) << 4);
    int esro[2][2];
    #pragma unroll
    for (int t = 0; t < 2; ++t)
        #pragma unroll
        for (int c = 0; c < 2; ++c) {
            const int rr = t * 16 + lr;
            esro[t][c] = rr * 128 + (((c * 4 + lg) ^ (rr & 7)) << 4);
        }
    int eswo[2][4];
    #pragma unroll
    for (int t = 0; t < 2; ++t)
        #pragma unroll
        for (int r = 0; r < 4; ++r) {
            const int n = t * 16 + lg * 4 + r;
            eswo[t][r] = n * 128 + (((w * 2 + (lr >> 3)) ^ (n & 7)) << 4) + (lr & 7) * 2;
        }

    // =============== PASS A: l[n] = sum_a exp(S[n][a]) ===============
    u32x4 kr0 = *(const u32x4*)(Kb + lin0);
    u32x4 kr1 = *(const u32x4*)(Kb + lin1);
    *(u32x4*)(smem + KD0 + kdst0) = kr0;
    *(u32x4*)(smem + KD0 + kdst1) = kr1;
    bar_lgkm();

    float lacc[2][4] = {};
    for (int i = 0; i < NT; ++i) {
        const int p = i & 1;
        if (i + 1 < NT) {
            kr0 = *(const u32x4*)(Kb + (i + 1) * 8192 + lin0);
            kr1 = *(const u32x4*)(Kb + (i + 1) * 8192 + lin1);
        }
        const char* kbuf = smem + (p ? KD1 : KD0);
        u32x4 kf0 = *(const u32x4*)(kbuf + kfro[0]);
        u32x4 kf1 = *(const u32x4*)(kbuf + kfro[1]);
        #pragma unroll
        for (int t = 0; t < 2; ++t) {
            f32x4 acc = {0.f, 0.f, 0.f, 0.f};
            acc = mfma_bf16(af[t][0], kf0, acc);
            acc = mfma_bf16(af[t][1], kf1, acc);
            #pragma unroll
            for (int r = 0; r < 4; ++r)
                lacc[t][r] += __expf(acc[r] * 0.125f);
        }
        if (i + 1 < NT) {
            char* kbn = smem + (p ? KD0 : KD1);
            *(u32x4*)(kbn + kdst0) = kr0;
            *(u32x4*)(kbn + kdst1) = kr1;
        }
        bar_lgkm();
    }

    // reduce l: over 16 a-lanes (shfl), then over 4 waves (LDS)
    #pragma unroll
    for (int t = 0; t < 2; ++t)
        #pragma unroll
        for (int r = 0; r < 4; ++r) {
            float v = lacc[t][r];
            v += __shfl_xor(v, 1); v += __shfl_xor(v, 2);
            v += __shfl_xor(v, 4); v += __shfl_xor(v, 8);
            lacc[t][r] = v;
        }
    if (lr == 0) {
        float* lp = (float*)(smem + LRED);
        #pragma unroll
        for (int t = 0; t < 2; ++t)
            #pragma unroll
            for (int r = 0; r < 4; ++r)
                lp[w * 32 + t * 16 + lg * 4 + r] = lacc[t][r];
    }
    __syncthreads();
    if (tid < 32) {
        const float* lp = (const float*)(smem + LRED);
        ((float*)(smem + LINV))[tid] =
            1.0f / (lp[tid] + lp[32 + tid] + lp[64 + tid] + lp[96 + tid]);
    }
    __syncthreads();
    f32x4 linv[2];
    linv[0] = *(const f32x4*)(smem + LINV + (lg * 4) * 4);
    linv[1] = *(const f32x4*)(smem + LINV + (16 + lg * 4) * 4);

    // =============== PASS B: w = e/l (store), PV accumulate ===============
    f32x4 pacc[2] = {{0.f,0.f,0.f,0.f},{0.f,0.f,0.f,0.f}};

    kr0 = *(const u32x4*)(Kb + lin0);
    kr1 = *(const u32x4*)(Kb + lin1);
    u32x4 vr0 = *(const u32x4*)(Vt + vsrc0);
    u32x4 vr1 = *(const u32x4*)(Vt + vsrc1);
    *(u32x4*)(smem + KD0 + kdst0) = kr0;
    *(u32x4*)(smem + KD0 + kdst1) = kr1;
    *(u32x4*)(smem + VD0 + kdst0) = vr0;
    *(u32x4*)(smem + VD0 + kdst1) = vr1;
    bar_lgkm();

    for (int i = 0; i < NT; ++i) {
        const int p = i & 1;
        if (i + 1 < NT) {
            kr0 = *(const u32x4*)(Kb + (i + 1) * 8192 + lin0);
            kr1 = *(const u32x4*)(Kb + (i + 1) * 8192 + lin1);
            vr0 = *(const u32x4*)(Vt + (i + 1) * 128 + vsrc0);
            vr1 = *(const u32x4*)(Vt + (i + 1) * 128 + vsrc1);
        }
        const char* kbuf = smem + (p ? KD1 : KD0);
        const char* vbuf = smem + (p ? VD1 : VD0);
        u32x4 kf0 = *(const u32x4*)(kbuf + kfro[0]);
        u32x4 kf1 = *(const u32x4*)(kbuf + kfro[1]);
        const int at = i * 64;
        #pragma unroll
        for (int t = 0; t < 2; ++t) {
            f32x4 acc = {0.f, 0.f, 0.f, 0.f};
            acc = mfma_bf16(af[t][0], kf0, acc);
            acc = mfma_bf16(af[t][1], kf1, acc);
            f32x4 wv;
            #pragma unroll
            for (int r = 0; r < 4; ++r)
                wv[r] = __expf(acc[r] * 0.125f) * linv[t][r];
            *(f32x4*)(Wb + (size_t)(at + row) * NB + nb + t * 16 + lg * 4) = wv;
            #pragma unroll
            for (int r = 0; r < 4; ++r)
                *(unsigned short*)(smem + ESB + eswo[t][r]) = f2bf(wv[r]);
        }
        bar_lgkm();   // Es visible; prefetch global loads stay in flight

        u32x4 pa[2][2];
        #pragma unroll
        for (int t = 0; t < 2; ++t)
            #pragma unroll
            for (int c = 0; c < 2; ++c)
                pa[t][c] = *(const u32x4*)(smem + ESB + esro[t][c]);
        u32x4 vf0 = *(const u32x4*)(vbuf + kfro[0]);
        u32x4 vf1 = *(const u32x4*)(vbuf + kfro[1]);
        #pragma unroll
        for (int t = 0; t < 2; ++t) {
            pacc[t] = mfma_bf16(pa[t][0], vf0, pacc[t]);
            pacc[t] = mfma_bf16(pa[t][1], vf1, pacc[t]);
        }
        if (i + 1 < NT) {
            char* kbn = smem + (p ? KD0 : KD1);
            char* vbn = smem + (p ? VD0 : VD1);
            *(u32x4*)(kbn + kdst0) = kr0;
            *(u32x4*)(kbn + kdst1) = kr1;
            *(u32x4*)(vbn + kdst0) = vr0;
            *(u32x4*)(vbn + kdst1) = vr1;
        }
        bar_lgkm();
    }

    // =============== epilogue: normalize over v (ddof=1), transpose, store ===============
    __syncthreads();
    float* vals = (float*)smem;   // [32][66], aliases Kd
    #pragma unroll
    for (int t = 0; t < 2; ++t)
        #pragma unroll
        for (int r = 0; r < 4; ++r)
            vals[(t * 16 + lg * 4 + r) * 66 + w * 16 + lr] = pacc[t][r];
    __syncthreads();
    {
        const int n = tid >> 3, v0 = (tid & 7) * 8;
        float sv[8], s1 = 0.f, s2 = 0.f;
        #pragma unroll
        for (int j = 0; j < 8; ++j) {
            float x = vals[n * 66 + v0 + j];
            sv[j] = x; s1 += x; s2 = fmaf(x, x, s2);
        }
        s1 += __shfl_xor(s1, 1); s2 += __shfl_xor(s2, 1);
        s1 += __shfl_xor(s1, 2); s2 += __shfl_xor(s2, 2);
        s1 += __shfl_xor(s1, 4); s2 += __shfl_xor(s2, 4);
        const float mu = s1 * (1.0f / 64.0f);
        float var = (s2 - 64.0f * mu * mu) * (1.0f / 63.0f);
        var = fmaxf(var, 0.0f);
        const float istd = 1.0f / (sqrtf(var) + EPS);
        #pragma unroll
        for (int j = 0; j < 8; ++j)
            vals[n * 66 + v0 + j] = (sv[j] - mu) * istd;
    }
    __syncthreads();
    {
        const int v = tid >> 2, q = (tid & 3) * 8;
        f32x4 o0, o1;
        #pragma unroll
        for (int j = 0; j < 4; ++j) o0[j] = vals[(q + j) * 66 + v];
        #pragma unroll
        for (int j = 0; j < 4; ++j) o1[j] = vals[(q + 4 + j) * 66 + v];
        *(f32x4*)(Ob + (size_t)v * NB + nb + q) = o0;
        *(f32x4*)(Ob + (size_t)v * NB + nb + q + 4) = o1;
    }
}

// ======================= fallback (round-2 kernel) =======================
#define SQ 72
#define OSTR 68
#define SMEM_BYTES 38144

__global__ __launch_bounds__(256, 2)
void attn_fb_kernel(const float* __restrict__ key, const float* __restrict__ query,
                    const float* __restrict__ value, float* __restrict__ out,
                    float* __restrict__ wout)
{
    __shared__ __align__(16) char smem[SMEM_BYTES];
    unsigned short* Qs = (unsigned short*)(smem);
    unsigned short* Ks = (unsigned short*)(smem + 9216);
    unsigned short* Vts = (unsigned short*)(smem + 18432);
    unsigned short* Es = (unsigned short*)(smem + 27648);
    float* linv_s = (float*)(smem + 36864);
    float (*lred)[64] = (float (*)[64])(smem + 37120);
    float* outl = (float*)(smem + 18432);

    const int tid = threadIdx.x, wave = tid >> 6, lane = tid & 63;
    const int lr = lane & 15, lg = lane >> 4;
    const int b = blockIdx.y, nb = blockIdx.x * 64, aw = wave * 16;

    const float* Kb = key + (size_t)b * NA * NK;
    const float* Qb = query + (size_t)b * NB * NK;
    const float* Vb = value + (size_t)b * NA * NV;
    float* Wb = wout + (size_t)b * NA * NB;
    float* Ob = out + (size_t)b * NV * NB;

    {
        const int r = tid >> 2, c = (tid & 3) * 16;
        const float* src = Qb + (size_t)(nb + r) * NK + c;
        f32x4 q0 = ldg4(src), q1 = ldg4(src + 4), q2 = ldg4(src + 8), q3 = ldg4(src + 12);
        *(u16x8*)&Qs[r * SQ + c] = pk8(q0, q1);
        *(u16x8*)&Qs[r * SQ + c + 8] = pk8(q2, q3);
    }
    float lacc[4][4] = {};
    for (int at = 0; at < NA; at += 64) {
        {
            const int r = tid >> 2, c = (tid & 3) * 16;
            const float* src = Kb + (size_t)(at + r) * NK + c;
            f32x4 k0 = ldg4(src), k1 = ldg4(src + 4), k2 = ldg4(src + 8), k3 = ldg4(src + 12);
            *(u16x8*)&Ks[r * SQ + c] = pk8(k0, k1);
            *(u16x8*)&Ks[r * SQ + c + 8] = pk8(k2, k3);
        }
        __syncthreads();
        u32x4 bf0 = *(const u32x4*)&Ks[(aw + lr) * SQ + (lg * 8)];
        u32x4 bf1 = *(const u32x4*)&Ks[(aw + lr) * SQ + (32 + lg * 8)];
        #pragma unroll
        for (int t = 0; t < 4; ++t) {
            f32x4 acc = {0.f, 0.f, 0.f, 0.f};
            u32x4 af0 = *(const u32x4*)&Qs[(t * 16 + lr) * SQ + (lg * 8)];
            u32x4 af1 = *(const u32x4*)&Qs[(t * 16 + lr) * SQ + (32 + lg * 8)];
            acc = mfma_bf16(af0, bf0, acc);
            acc = mfma_bf16(af1, bf1, acc);
            #pragma unroll
            for (int r = 0; r < 4; ++r) lacc[t][r] += __expf(acc[r] * 0.125f);
        }
        __syncthreads();
    }
    #pragma unroll
    for (int t = 0; t < 4; ++t)
        #pragma unroll
        for (int r = 0; r < 4; ++r) {
            float v = lacc[t][r];
            v += __shfl_xor(v, 1); v += __shfl_xor(v, 2);
            v += __shfl_xor(v, 4); v += __shfl_xor(v, 8);
            lacc[t][r] = v;
        }
    if (lr == 0)
        #pragma unroll
        for (int t = 0; t < 4; ++t)
            #pragma unroll
            for (int r = 0; r < 4; ++r)
                lred[wave][t * 16 + lg * 4 + r] = lacc[t][r];
    __syncthreads();
    if (tid < 64) {
        float s = lred[0][tid] + lred[1][tid] + lred[2][tid] + lred[3][tid];
        linv_s[tid] = 1.0f / s;
    }
    __syncthreads();
    f32x4 linv[4];
    #pragma unroll
    for (int t = 0; t < 4; ++t) linv[t] = *(const f32x4*)&linv_s[t * 16 + lg * 4];

    f32x4 pacc[4] = {{0.f,0.f,0.f,0.f},{0.f,0.f,0.f,0.f},{0.f,0.f,0.f,0.f},{0.f,0.f,0.f,0.f}};
    for (int at = 0; at < NA; at += 64) {
        {
            const int r = tid >> 2, c = (tid & 3) * 16;
            const float* src = Kb + (size_t)(at + r) * NK + c;
            f32x4 k0 = ldg4(src), k1 = ldg4(src + 4), k2 = ldg4(src + 8), k3 = ldg4(src + 12);
            *(u16x8*)&Ks[r * SQ + c] = pk8(k0, k1);
            *(u16x8*)&Ks[r * SQ + c + 8] = pk8(k2, k3);
        }
        {
            const int ap = (tid & 31) * 2, q = tid >> 5;
            const float* v0p = Vb + (size_t)(at + ap) * NV + q * 8;
            const float* v1p = v0p + NV;
            f32x4 a0 = ldg4(v0p), a1 = ldg4(v0p + 4);
            f32x4 b0 = ldg4(v1p), b1 = ldg4(v1p + 4);
            #pragma unroll
            for (int j = 0; j < 4; ++j) {
                unsigned int w0 = (unsigned)f2bf(a0[j]) | ((unsigned)f2bf(b0[j]) << 16);
                *(unsigned int*)&Vts[(q * 8 + j) * SQ + ap] = w0;
                unsigned int w1 = (unsigned)f2bf(a1[j]) | ((unsigned)f2bf(b1[j]) << 16);
                *(unsigned int*)&Vts[(q * 8 + 4 + j) * SQ + ap] = w1;
            }
        }
        __syncthreads();
        u32x4 bf0 = *(const u32x4*)&Ks[(aw + lr) * SQ + (lg * 8)];
        u32x4 bf1 = *(const u32x4*)&Ks[(aw + lr) * SQ + (32 + lg * 8)];
        #pragma unroll
        for (int t = 0; t < 4; ++t) {
            f32x4 acc = {0.f, 0.f, 0.f, 0.f};
            u32x4 af0 = *(const u32x4*)&Qs[(t * 16 + lr) * SQ + (lg * 8)];
            u32x4 af1 = *(const u32x4*)&Qs[(t * 16 + lr) * SQ + (32 + lg * 8)];
            acc = mfma_bf16(af0, bf0, acc);
            acc = mfma_bf16(af1, bf1, acc);
            f32x4 wv;
            #pragma unroll
            for (int r = 0; r < 4; ++r) wv[r] = __expf(acc[r] * 0.125f) * linv[t][r];
            *(f32x4*)(Wb + (size_t)(at + aw + lr) * NB + nb + t * 16 + lg * 4) = wv;
            #pragma unroll
            for (int r = 0; r < 4; ++r)
                Es[(t * 16 + lg * 4 + r) * SQ + (aw + lr)] = f2bf(wv[r]);
        }
        __syncthreads();
        u32x4 paf0 = *(const u32x4*)&Es[(wave * 16 + lr) * SQ + (lg * 8)];
        u32x4 paf1 = *(const u32x4*)&Es[(wave * 16 + lr) * SQ + (32 + lg * 8)];
        #pragma unroll
        for (int t = 0; t < 4; ++t) {
            u32x4 vb0 = *(const u32x4*)&Vts[(t * 16 + lr) * SQ + (lg * 8)];
            u32x4 vb1 = *(const u32x4*)&Vts[(t * 16 + lr) * SQ + (32 + lg * 8)];
            pacc[t] = mfma_bf16(paf0, vb0, pacc[t]);
            pacc[t] = mfma_bf16(paf1, vb1, pacc[t]);
        }
        __syncthreads();
    }
    float mu[4], istd[4];
    #pragma unroll
    for (int r = 0; r < 4; ++r) {
        float s1 = 0.f, s2 = 0.f;
        #pragma unroll
        for (int t = 0; t < 4; ++t) { float x = pacc[t][r]; s1 += x; s2 = fmaf(x, x, s2); }
        s1 += __shfl_xor(s1, 1); s2 += __shfl_xor(s2, 1);
        s1 += __shfl_xor(s1, 2); s2 += __shfl_xor(s2, 2);
        s1 += __shfl_xor(s1, 4); s2 += __shfl_xor(s2, 4);
        s1 += __shfl_xor(s1, 8); s2 += __shfl_xor(s2, 8);
        float m = s1 * (1.0f / 64.0f);
        float var = (s2 - 64.0f * m * m) * (1.0f / 63.0f);
        var = fmaxf(var, 0.0f);
        mu[r] = m; istd[r] = 1.0f / (sqrtf(var) + EPS);
    }
    #pragma unroll
    for (int t = 0; t < 4; ++t)
        #pragma unroll
        for (int r = 0; r < 4; ++r)
            outl[(t * 16 + lr) * OSTR + wave * 16 + lg * 4 + r] = (pacc[t][r] - mu[r]) * istd[r];
    __syncthreads();
    {
        const int v = tid >> 2, c = (tid & 3) * 16;
        float* dst = Ob + (size_t)v * NB + nb + c;
        const float* srcr = &outl[v * OSTR + c];
        #pragma unroll
        for (int j = 0; j < 4; ++j)
            *(f32x4*)(dst + 4 * j) = *(const f32x4*)(srcr + 4 * j);
    }
}

extern "C" void kernel_launch(void* const* d_in, const int* in_sizes, int n_in,
                              void* d_out, int out_size, void* d_ws, size_t ws_size,
                              hipStream_t stream) {
    const float* key   = (const float*)d_in[0];
    const float* query = (const float*)d_in[1];
    const float* value = (const float*)d_in[2];
    float* out  = (float*)d_out;                   // [BS][NV][NB]
    float* wout = out + (size_t)BS * NV * NB;      // [BS][NA][NB]

    const size_t elems = (size_t)BS * NA * NK;     // 2,097,152 per array
    const size_t need = 2 * elems * sizeof(unsigned short);
    if (ws_size >= need) {
        unsigned short* kbuf = (unsigned short*)d_ws;
        unsigned short* vt = kbuf + elems;
        conv_k_kernel<<<dim3((unsigned)(elems / (256 * 8))), 256, 0, stream>>>(key, kbuf);
        transpose_v_kernel<<<dim3(NA / 64, BS), 256, 0, stream>>>(value, vt);
        attn_main7_kernel<<<dim3(1024), 256, 0, stream>>>(kbuf, query, vt, out, wout);
    } else {
        attn_fb_kernel<<<dim3(NB / 64, BS), 256, 0, stream>>>(key, query, value, out, wout);
    }
}